// Round 9
// baseline (1233.215 us; speedup 1.0000x reference)
//
#include <hip/hip_runtime.h>

#define NPTS 4096
#define BATCH 4
#define KNN 20
#define ROT 116

__device__ __forceinline__ void vn_lrelu3(float p[3], const float d[3]) {
  float dot = p[0]*d[0] + p[1]*d[1] + p[2]*d[2];
  if (dot < 0.0f) {
    float dsq = d[0]*d[0] + d[1]*d[1] + d[2]*d[2];
    float r = dot / (dsq + 1e-6f);
    p[0] -= r*d[0]; p[1] -= r*d[1]; p[2] -= r*d[2];
  }
}

// dual matvec over 64 channels: pf = Wf[c,:]@src, pd = Wd[c,:]@src (3-vectors)
// src rows are [64][4] float4-aligned; one wave = one point so src reads are
// same-address broadcasts (no bank conflicts). Weight rows stride 68 floats.
__device__ __forceinline__ void matvec2(const float wf[][68], const float wd[][68],
                                        const float src[][4], int c,
                                        float pf[3], float pd[3]) {
  float a0=0,a1=0,a2=0,b0=0,b1=0,b2=0;
#pragma unroll
  for (int i = 0; i < 64; i += 4) {
    const float4 f  = *(const float4*)&wf[c][i];
    const float4 d  = *(const float4*)&wd[c][i];
    const float4 h0 = *(const float4*)src[i+0];
    const float4 h1 = *(const float4*)src[i+1];
    const float4 h2 = *(const float4*)src[i+2];
    const float4 h3 = *(const float4*)src[i+3];
    a0 += f.x*h0.x + f.y*h1.x + f.z*h2.x + f.w*h3.x;
    a1 += f.x*h0.y + f.y*h1.y + f.z*h2.y + f.w*h3.y;
    a2 += f.x*h0.z + f.y*h1.z + f.z*h2.z + f.w*h3.z;
    b0 += d.x*h0.x + d.y*h1.x + d.z*h2.x + d.w*h3.x;
    b1 += d.x*h0.y + d.y*h1.y + d.z*h2.y + d.w*h3.y;
    b2 += d.x*h0.z + d.y*h1.z + d.z*h2.z + d.w*h3.z;
  }
  pf[0]=a0; pf[1]=a1; pf[2]=a2; pd[0]=b0; pd[1]=b1; pd[2]=b2;
}

// ---------------- K1: KNN via histogram select (unchanged) ----------------
__global__ __launch_bounds__(256) void knn_kernel(const float* __restrict__ x,
                                                  int* __restrict__ knn) {
  const int row = blockIdx.x;
  const int b = row >> 12, i = row & (NPTS - 1);
  const float* __restrict__ xb = x + b * 3 * NPTS;
  const float cx = xb[i], cy = xb[NPTS + i], cz = xb[2 * NPTS + i];
  const int t = threadIdx.x;
  const int j0 = t << 4;

  __shared__ unsigned int hist[2048];
  __shared__ unsigned int ld_[384];
  __shared__ int lj_[384];
  __shared__ unsigned int lcount;
  __shared__ int s_B;
  __shared__ int wtot[4];

  for (int k = t; k < 2048; k += 256) hist[k] = 0u;
  if (t == 0) lcount = 0u;
  __syncthreads();

  unsigned int db[16];
#pragma unroll
  for (int q = 0; q < 4; ++q) {
    const float4 px = *(const float4*)(xb + j0 + 4 * q);
    const float4 py = *(const float4*)(xb + NPTS + j0 + 4 * q);
    const float4 pz = *(const float4*)(xb + 2 * NPTS + j0 + 4 * q);
    float dx, dy, dz, dd;
    dx = px.x - cx; dy = py.x - cy; dz = pz.x - cz;
    dd = dx*dx + dy*dy + dz*dz; db[4*q+0] = __float_as_uint(dd);
    dx = px.y - cx; dy = py.y - cy; dz = pz.y - cz;
    dd = dx*dx + dy*dy + dz*dz; db[4*q+1] = __float_as_uint(dd);
    dx = px.z - cx; dy = py.z - cy; dz = pz.z - cz;
    dd = dx*dx + dy*dy + dz*dz; db[4*q+2] = __float_as_uint(dd);
    dx = px.w - cx; dy = py.w - cy; dz = pz.w - cz;
    dd = dx*dx + dy*dy + dz*dz; db[4*q+3] = __float_as_uint(dd);
  }
#pragma unroll
  for (int s = 0; s < 16; ++s) atomicAdd(&hist[db[s] >> 20], 1u);
  __syncthreads();

  int v = 0;
#pragma unroll
  for (int s = 0; s < 8; ++s) v += (int)hist[t * 8 + s];
  const int myps = v;
  const int lane = t & 63;
#pragma unroll
  for (int off = 1; off < 64; off <<= 1) {
    int n = __shfl_up(v, off);
    if (lane >= off) v += n;
  }
  if (lane == 63) wtot[t >> 6] = v;
  __syncthreads();
  int woff = 0;
#pragma unroll
  for (int w = 0; w < 4; ++w) if (w < (t >> 6)) woff += wtot[w];
  const int cum_in = v + woff;
  const int cum_ex = cum_in - myps;
  if (cum_ex < KNN && cum_in >= KNN) {
    int cum = cum_ex, B = t * 8;
    for (int s = 0; s < 8; ++s) {
      const int hh = (int)hist[t * 8 + s];
      if (cum + hh >= KNN) { B = t * 8 + s; break; }
      cum += hh;
    }
    s_B = B;
  }
  __syncthreads();
  const unsigned int Bb = (unsigned int)s_B;
#pragma unroll
  for (int s = 0; s < 16; ++s) {
    if ((db[s] >> 20) <= Bb) {
      unsigned int pos = atomicAdd(&lcount, 1u);
      if (pos < 384u) { ld_[pos] = db[s]; lj_[pos] = j0 + s; }
    }
  }
  __syncthreads();
  const int n = min((int)lcount, 384);
  for (int idx = t; idx < n; idx += 256) {
    const unsigned int kd = ld_[idx]; const int kj = lj_[idx];
    int rank = 0;
    for (int m = 0; m < n; ++m) {
      const unsigned int md = ld_[m];
      rank += (md < kd || (md == kd && lj_[m] < kj)) ? 1 : 0;
    }
    if (rank < KNN) knn[row * KNN + rank] = kj;
  }
}

// ------- K2: edge features + first VNT layer + mean over k (4 pts/block) -------
__global__ __launch_bounds__(256) void edge_kernel(const float* __restrict__ x,
                                                   const int* __restrict__ knn,
                                                   const float* __restrict__ Wf,
                                                   const float* __restrict__ Wd,
                                                   float* __restrict__ h) {
  const int g = threadIdx.x >> 6;
  const int lane = threadIdx.x & 63;
  const int p = (blockIdx.x << 2) + g;
  const int b = p >> 12, i = p & (NPTS - 1);
  const float* xb = x + b * 3 * NPTS;
  const float cx = xb[i], cy = xb[NPTS + i], cz = xb[2 * NPTS + i];
  __shared__ float e[4][KNN][3][3];
  if (lane < KNN) {
    int j = knn[p * KNN + lane];
    float nx = xb[j], ny = xb[NPTS + j], nz = xb[2 * NPTS + j];
    e[g][lane][0][0] = nx - cx; e[g][lane][0][1] = ny - cy; e[g][lane][0][2] = nz - cz;
    e[g][lane][1][0] = cx;      e[g][lane][1][1] = cy;      e[g][lane][1][2] = cz;
    e[g][lane][2][0] = ny * cz - nz * cy;
    e[g][lane][2][1] = nz * cx - nx * cz;
    e[g][lane][2][2] = nx * cy - ny * cx;
  }
  __syncthreads();
  const int c = lane;
  float f0 = Wf[c * 3 + 0], f1 = Wf[c * 3 + 1], f2 = Wf[c * 3 + 2];
  float s = 1.0f / (f0 + f1 + f2);
  f0 *= s; f1 *= s; f2 *= s;
  const float d0 = Wd[c * 3 + 0], d1 = Wd[c * 3 + 1], d2 = Wd[c * 3 + 2];
  float a0 = 0.f, a1 = 0.f, a2 = 0.f;
  for (int k = 0; k < KNN; ++k) {
    float pv[3], dv[3];
#pragma unroll
    for (int v = 0; v < 3; ++v) {
      pv[v] = f0 * e[g][k][0][v] + f1 * e[g][k][1][v] + f2 * e[g][k][2][v];
      dv[v] = d0 * e[g][k][0][v] + d1 * e[g][k][1][v] + d2 * e[g][k][2][v];
    }
    vn_lrelu3(pv, dv);
    a0 += pv[0]; a1 += pv[1]; a2 += pv[2];
  }
  const float inv = 1.0f / KNN;
  float* hp = h + p * 192 + c * 3;
  hp[0] = a0 * inv; hp[1] = a1 * inv; hp[2] = a2 * inv;
}

// ------- K3a: Wc1 -> Wc2 -> (hc = h - xc), Wt -> trans partials -------
// 1024 threads = 16 waves = 16 points per iter; 64 points per block; grid 256.
__global__ __launch_bounds__(1024) void center_kernel(
    const float* __restrict__ h,
    const float* __restrict__ Wc1f, const float* __restrict__ Wc1d,
    const float* __restrict__ Wc2f, const float* __restrict__ Wc2d,
    const float* __restrict__ Wtf,  const float* __restrict__ Wtd,
    float* __restrict__ hc, float* __restrict__ trans_part) {
  __shared__ float w1f[64][68], w1d[64][68], w2f[64][68], w2d[64][68];
  __shared__ float wtf[12][68], wtd[12][68];
  __shared__ float hin[16][64][4], tmp[16][64][4];
  __shared__ float tred[16][12][3];
  const int t = threadIdx.x;
  for (int e = t; e < 4096; e += 1024) {
    int r = e >> 6, cc = e & 63;
    w1f[r][cc] = Wc1f[e]; w1d[r][cc] = Wc1d[e];
    w2f[r][cc] = Wc2f[e]; w2d[r][cc] = Wc2d[e];
  }
  if (t < 768) { int r = t >> 6, cc = t & 63; wtf[r][cc] = Wtf[t]; wtd[r][cc] = Wtd[t]; }
  __syncthreads();
  if (t < 64) {                      // VNT row normalization
    float s = 0.f;
    for (int i = 0; i < 64; ++i) s += w1f[t][i];
    s = 1.0f / s;
    for (int i = 0; i < 64; ++i) w1f[t][i] *= s;
  } else if (t < 128) {
    int r = t - 64; float s = 0.f;
    for (int i = 0; i < 64; ++i) s += w2f[r][i];
    s = 1.0f / s;
    for (int i = 0; i < 64; ++i) w2f[r][i] *= s;
  } else if (t < 140) {
    int r = t - 128; float s = 0.f;
    for (int i = 0; i < 64; ++i) s += wtf[r][i];
    s = 1.0f / s;
    for (int i = 0; i < 64; ++i) wtf[r][i] *= s;
  }
  const int q = t >> 6, c = t & 63;
  const int blk = blockIdx.x;
  const int pbase = ((blk >> 6) << 12) + ((blk & 63) << 6);
  float tacc0 = 0.f, tacc1 = 0.f, tacc2 = 0.f;
  for (int g = 0; g < 4; ++g) {
    __syncthreads();
    const int p0 = pbase + (g << 4);
    for (int e = t; e < 3072; e += 1024) {
      int qq = e / 192, rr = e - qq * 192, ii = rr / 3, vv = rr - ii * 3;
      hin[qq][ii][vv] = h[p0 * 192 + e];
    }
    __syncthreads();
    float pf[3], pd[3];
    matvec2(w1f, w1d, hin[q], c, pf, pd);
    vn_lrelu3(pf, pd);
    *(float4*)tmp[q][c] = make_float4(pf[0], pf[1], pf[2], 0.f);
    __syncthreads();
    float qf[3], qd[3];
    matvec2(w2f, w2d, tmp[q], c, qf, qd);
    vn_lrelu3(qf, qd);                 // qf = xc
    const float4 hv = *(const float4*)hin[q][c];
    float* hcp = hc + (size_t)(p0 + q) * 192 + c * 3;
    hcp[0] = hv.x - qf[0]; hcp[1] = hv.y - qf[1]; hcp[2] = hv.z - qf[2];
    __syncthreads();
    *(float4*)tmp[q][c] = make_float4(qf[0], qf[1], qf[2], 0.f);   // xc
    __syncthreads();
    if (c < 12) {
      float tf[3], td[3];
      matvec2(wtf, wtd, tmp[q], c, tf, td);
      vn_lrelu3(tf, td);
      tacc0 += tf[0]; tacc1 += tf[1]; tacc2 += tf[2];
    }
  }
  __syncthreads();
  if (c < 12) { tred[q][c][0] = tacc0; tred[q][c][1] = tacc1; tred[q][c][2] = tacc2; }
  __syncthreads();
  if (t < 36) {
    int cc = t / 3, vv = t - cc * 3;
    float s = 0.f;
#pragma unroll
    for (int q2 = 0; q2 < 16; ++q2) s += tred[q2][cc][vv];
    trans_part[blk * 36 + t] = s;
  }
}

// ------- K3b: W1 -> W2 -> sum h2 over points (conv3 moved past the mean) -------
__global__ __launch_bounds__(1024) void rot_kernel(
    const float* __restrict__ hc,
    const float* __restrict__ W1f, const float* __restrict__ W1d,
    const float* __restrict__ W2f, const float* __restrict__ W2d,
    float* __restrict__ rot_part) {
  __shared__ float w1f[64][68], w1d[64][68], w2f[64][68], w2d[64][68];
  __shared__ float hin[16][64][4], tmp[16][64][4];
  const int t = threadIdx.x;
  for (int e = t; e < 4096; e += 1024) {
    int r = e >> 6, cc = e & 63;
    w1f[r][cc] = W1f[e]; w1d[r][cc] = W1d[e];
    w2f[r][cc] = W2f[e]; w2d[r][cc] = W2d[e];
  }
  const int q = t >> 6, c = t & 63;
  const int blk = blockIdx.x;
  const int pbase = ((blk >> 6) << 12) + ((blk & 63) << 6);
  float r0 = 0.f, r1 = 0.f, r2 = 0.f;
  for (int g = 0; g < 4; ++g) {
    __syncthreads();
    const int p0 = pbase + (g << 4);
    for (int e = t; e < 3072; e += 1024) {
      int qq = e / 192, rr = e - qq * 192, ii = rr / 3, vv = rr - ii * 3;
      hin[qq][ii][vv] = hc[p0 * 192 + e];
    }
    __syncthreads();
    float pf[3], pd[3];
    matvec2(w1f, w1d, hin[q], c, pf, pd);
    vn_lrelu3(pf, pd);
    *(float4*)tmp[q][c] = make_float4(pf[0], pf[1], pf[2], 0.f);
    __syncthreads();
    float qf[3], qd[3];
    matvec2(w2f, w2d, tmp[q], c, qf, qd);
    vn_lrelu3(qf, qd);                 // h2
    r0 += qf[0]; r1 += qf[1]; r2 += qf[2];
  }
  __syncthreads();
  *(float4*)hin[q][c] = make_float4(r0, r1, r2, 0.f);
  __syncthreads();
  if (t < 192) {
    int cc = t / 3, vv = t - cc * 3;
    float s = 0.f;
#pragma unroll
    for (int q2 = 0; q2 < 16; ++q2) s += hin[q2][cc][vv];
    rot_part[blk * 192 + t] = s;
  }
}

// ------- K4: reduce partials, W3 @ mean(h2), /N, concat [rot(116), trans(12)] -------
__global__ __launch_bounds__(384) void finalize_kernel(const float* __restrict__ rot_part,
                                                       const float* __restrict__ trans_part,
                                                       const float* __restrict__ W3,
                                                       float* __restrict__ out) {
  const int b = blockIdx.x;   // 0..3
  const int t = threadIdx.x;
  __shared__ float hsum[64][3];
  if (t < 192) {
    float s = 0.f;
    for (int blk = 0; blk < 64; ++blk)
      s += rot_part[(b * 64 + blk) * 192 + t];
    hsum[t / 3][t % 3] = s * (1.0f / NPTS);
  } else if (t < 228) {
    const int tt = t - 192;
    float s = 0.f;
    for (int blk = 0; blk < 64; ++blk)
      s += trans_part[(b * 64 + blk) * 36 + tt];
    out[b * 384 + 348 + tt] = s * (1.0f / NPTS);
  }
  __syncthreads();
  if (t < 348) {
    const int ch = t / 3, v = t - ch * 3;
    float s = 0.f;
    for (int i = 0; i < 64; ++i) s += W3[ch * 64 + i] * hsum[i][v];
    out[b * 384 + t] = s;
  }
}

extern "C" void kernel_launch(void* const* d_in, const int* in_sizes, int n_in,
                              void* d_out, int out_size, void* d_ws, size_t ws_size,
                              hipStream_t stream) {
  (void)in_sizes; (void)n_in; (void)out_size; (void)ws_size;
  const float* x     = (const float*)d_in[0];
  const float* Wposf = (const float*)d_in[1];
  const float* Wposd = (const float*)d_in[2];
  const float* Wc1f  = (const float*)d_in[3];
  const float* Wc1d  = (const float*)d_in[4];
  const float* Wc2f  = (const float*)d_in[5];
  const float* Wc2d  = (const float*)d_in[6];
  const float* Wtf   = (const float*)d_in[7];
  const float* Wtd   = (const float*)d_in[8];
  const float* W1f   = (const float*)d_in[9];
  const float* W1d   = (const float*)d_in[10];
  const float* W2f   = (const float*)d_in[11];
  const float* W2d   = (const float*)d_in[12];
  const float* W3    = (const float*)d_in[13];
  float* out = (float*)d_out;

  char* ws = (char*)d_ws;
  int*   knn        = (int*)ws;                                      // 1,310,720 B
  float* h          = (float*)(ws + 1310720);                        // 12,582,912 B
  float* hcbuf      = (float*)(ws + 1310720 + 12582912);             // 12,582,912 B
  float* trans_part = (float*)(ws + 1310720 + 2 * 12582912);         // 256*36*4  = 36,864 B
  float* rot_part   = (float*)(ws + 1310720 + 2 * 12582912 + 36864); // 256*192*4 = 196,608 B

  knn_kernel<<<BATCH * NPTS, 256, 0, stream>>>(x, knn);
  edge_kernel<<<BATCH * NPTS / 4, 256, 0, stream>>>(x, knn, Wposf, Wposd, h);
  center_kernel<<<256, 1024, 0, stream>>>(h, Wc1f, Wc1d, Wc2f, Wc2d, Wtf, Wtd,
                                          hcbuf, trans_part);
  rot_kernel<<<256, 1024, 0, stream>>>(hcbuf, W1f, W1d, W2f, W2d, rot_part);
  finalize_kernel<<<BATCH, 384, 0, stream>>>(rot_part, trans_part, W3, out);
}

// Round 12
// 693.182 us; speedup vs baseline: 1.7791x; 1.7791x over previous
//
#include <hip/hip_runtime.h>

#define NPTS 4096
#define BATCH 4
#define KNN 20
#define ROT 116

__device__ __forceinline__ void vn_lrelu3(float p[3], const float d[3]) {
  float dot = p[0]*d[0] + p[1]*d[1] + p[2]*d[2];
  if (dot < 0.0f) {
    float dsq = d[0]*d[0] + d[1]*d[1] + d[2]*d[2];
    float r = dot / (dsq + 1e-6f);
    p[0] -= r*d[0]; p[1] -= r*d[1]; p[2] -= r*d[2];
  }
}

// dual matvec over 64 channels: pf = Wf[c,:]@src, pd = Wd[c,:]@src (3-vectors).
// src rows [64][4] float4-aligned; one wave = one point so src reads are
// same-address broadcasts. Weight rows stride 68 floats.
__device__ __forceinline__ void matvec2(const float wf[][68], const float wd[][68],
                                        const float src[][4], int c,
                                        float pf[3], float pd[3]) {
  float a0=0,a1=0,a2=0,b0=0,b1=0,b2=0;
#pragma unroll
  for (int i = 0; i < 64; i += 4) {
    const float4 f  = *(const float4*)&wf[c][i];
    const float4 d  = *(const float4*)&wd[c][i];
    const float4 h0 = *(const float4*)src[i+0];
    const float4 h1 = *(const float4*)src[i+1];
    const float4 h2 = *(const float4*)src[i+2];
    const float4 h3 = *(const float4*)src[i+3];
    a0 += f.x*h0.x + f.y*h1.x + f.z*h2.x + f.w*h3.x;
    a1 += f.x*h0.y + f.y*h1.y + f.z*h2.y + f.w*h3.y;
    a2 += f.x*h0.z + f.y*h1.z + f.z*h2.z + f.w*h3.z;
    b0 += d.x*h0.x + d.y*h1.x + d.z*h2.x + d.w*h3.x;
    b1 += d.x*h0.y + d.y*h1.y + d.z*h2.y + d.w*h3.y;
    b2 += d.x*h0.z + d.y*h1.z + d.z*h2.z + d.w*h3.z;
  }
  pf[0]=a0; pf[1]=a1; pf[2]=a2; pd[0]=b0; pd[1]=b1; pd[2]=b2;
}

// ---------------- K1: KNN via histogram select (unchanged) ----------------
__global__ __launch_bounds__(256) void knn_kernel(const float* __restrict__ x,
                                                  int* __restrict__ knn) {
  const int row = blockIdx.x;
  const int b = row >> 12, i = row & (NPTS - 1);
  const float* __restrict__ xb = x + b * 3 * NPTS;
  const float cx = xb[i], cy = xb[NPTS + i], cz = xb[2 * NPTS + i];
  const int t = threadIdx.x;
  const int j0 = t << 4;

  __shared__ unsigned int hist[2048];
  __shared__ unsigned int ld_[384];
  __shared__ int lj_[384];
  __shared__ unsigned int lcount;
  __shared__ int s_B;
  __shared__ int wtot[4];

  for (int k = t; k < 2048; k += 256) hist[k] = 0u;
  if (t == 0) lcount = 0u;
  __syncthreads();

  unsigned int db[16];
#pragma unroll
  for (int q = 0; q < 4; ++q) {
    const float4 px = *(const float4*)(xb + j0 + 4 * q);
    const float4 py = *(const float4*)(xb + NPTS + j0 + 4 * q);
    const float4 pz = *(const float4*)(xb + 2 * NPTS + j0 + 4 * q);
    float dx, dy, dz, dd;
    dx = px.x - cx; dy = py.x - cy; dz = pz.x - cz;
    dd = dx*dx + dy*dy + dz*dz; db[4*q+0] = __float_as_uint(dd);
    dx = px.y - cx; dy = py.y - cy; dz = pz.y - cz;
    dd = dx*dx + dy*dy + dz*dz; db[4*q+1] = __float_as_uint(dd);
    dx = px.z - cx; dy = py.z - cy; dz = pz.z - cz;
    dd = dx*dx + dy*dy + dz*dz; db[4*q+2] = __float_as_uint(dd);
    dx = px.w - cx; dy = py.w - cy; dz = pz.w - cz;
    dd = dx*dx + dy*dy + dz*dz; db[4*q+3] = __float_as_uint(dd);
  }
#pragma unroll
  for (int s = 0; s < 16; ++s) atomicAdd(&hist[db[s] >> 20], 1u);
  __syncthreads();

  int v = 0;
#pragma unroll
  for (int s = 0; s < 8; ++s) v += (int)hist[t * 8 + s];
  const int myps = v;
  const int lane = t & 63;
#pragma unroll
  for (int off = 1; off < 64; off <<= 1) {
    int n = __shfl_up(v, off);
    if (lane >= off) v += n;
  }
  if (lane == 63) wtot[t >> 6] = v;
  __syncthreads();
  int woff = 0;
#pragma unroll
  for (int w = 0; w < 4; ++w) if (w < (t >> 6)) woff += wtot[w];
  const int cum_in = v + woff;
  const int cum_ex = cum_in - myps;
  if (cum_ex < KNN && cum_in >= KNN) {
    int cum = cum_ex, B = t * 8;
    for (int s = 0; s < 8; ++s) {
      const int hh = (int)hist[t * 8 + s];
      if (cum + hh >= KNN) { B = t * 8 + s; break; }
      cum += hh;
    }
    s_B = B;
  }
  __syncthreads();
  const unsigned int Bb = (unsigned int)s_B;
#pragma unroll
  for (int s = 0; s < 16; ++s) {
    if ((db[s] >> 20) <= Bb) {
      unsigned int pos = atomicAdd(&lcount, 1u);
      if (pos < 384u) { ld_[pos] = db[s]; lj_[pos] = j0 + s; }
    }
  }
  __syncthreads();
  const int n = min((int)lcount, 384);
  for (int idx = t; idx < n; idx += 256) {
    const unsigned int kd = ld_[idx]; const int kj = lj_[idx];
    int rank = 0;
    for (int m = 0; m < n; ++m) {
      const unsigned int md = ld_[m];
      rank += (md < kd || (md == kd && lj_[m] < kj)) ? 1 : 0;
    }
    if (rank < KNN) knn[row * KNN + rank] = kj;
  }
}

// ------- K2: edge features + first VNT layer + mean over k (4 pts/block) -------
__global__ __launch_bounds__(256) void edge_kernel(const float* __restrict__ x,
                                                   const int* __restrict__ knn,
                                                   const float* __restrict__ Wf,
                                                   const float* __restrict__ Wd,
                                                   float* __restrict__ h) {
  const int g = threadIdx.x >> 6;
  const int lane = threadIdx.x & 63;
  const int p = (blockIdx.x << 2) + g;
  const int b = p >> 12, i = p & (NPTS - 1);
  const float* xb = x + b * 3 * NPTS;
  const float cx = xb[i], cy = xb[NPTS + i], cz = xb[2 * NPTS + i];
  __shared__ float e[4][KNN][3][3];
  if (lane < KNN) {
    int j = knn[p * KNN + lane];
    float nx = xb[j], ny = xb[NPTS + j], nz = xb[2 * NPTS + j];
    e[g][lane][0][0] = nx - cx; e[g][lane][0][1] = ny - cy; e[g][lane][0][2] = nz - cz;
    e[g][lane][1][0] = cx;      e[g][lane][1][1] = cy;      e[g][lane][1][2] = cz;
    e[g][lane][2][0] = ny * cz - nz * cy;
    e[g][lane][2][1] = nz * cx - nx * cz;
    e[g][lane][2][2] = nx * cy - ny * cx;
  }
  __syncthreads();
  const int c = lane;
  float f0 = Wf[c * 3 + 0], f1 = Wf[c * 3 + 1], f2 = Wf[c * 3 + 2];
  float s = 1.0f / (f0 + f1 + f2);
  f0 *= s; f1 *= s; f2 *= s;
  const float d0 = Wd[c * 3 + 0], d1 = Wd[c * 3 + 1], d2 = Wd[c * 3 + 2];
  float a0 = 0.f, a1 = 0.f, a2 = 0.f;
  for (int k = 0; k < KNN; ++k) {
    float pv[3], dv[3];
#pragma unroll
    for (int v = 0; v < 3; ++v) {
      pv[v] = f0 * e[g][k][0][v] + f1 * e[g][k][1][v] + f2 * e[g][k][2][v];
      dv[v] = d0 * e[g][k][0][v] + d1 * e[g][k][1][v] + d2 * e[g][k][2][v];
    }
    vn_lrelu3(pv, dv);
    a0 += pv[0]; a1 += pv[1]; a2 += pv[2];
  }
  const float inv = 1.0f / KNN;
  float* hp = h + p * 192 + c * 3;
  hp[0] = a0 * inv; hp[1] = a1 * inv; hp[2] = a2 * inv;
}

// ------- K3: one 64->64 VN(T) layer. 256 thr = 4 waves, 1 point/wave,
//         grid 1024, 16 points/block. LDS 38.8 KB -> 4 blocks/CU. -------
template<bool VNT>
__global__ __launch_bounds__(256, 4) void layer_kernel(
    const float* __restrict__ in,
    const float* __restrict__ Wf, const float* __restrict__ Wd,
    float* __restrict__ out) {
  __shared__ float wf[64][68], wd[64][68];
  __shared__ float hin[4][64][4];
  const int t = threadIdx.x;
  for (int e = t; e < 4096; e += 256) {
    wf[e >> 6][e & 63] = Wf[e]; wd[e >> 6][e & 63] = Wd[e];
  }
  __syncthreads();
  if (VNT) {
    if (t < 64) {
      float s = 0.f;
      for (int i = 0; i < 64; ++i) s += wf[t][i];
      s = 1.0f / s;
      for (int i = 0; i < 64; ++i) wf[t][i] *= s;
    }
    __syncthreads();
  }
  const int q = t >> 6, c = t & 63;
  for (int g = 0; g < 4; ++g) {
    const int p = (blockIdx.x << 4) + (g << 2) + q;
    const float* ip = in + (size_t)p * 192 + c * 3;
    // wave-private hin[q]; wave64 in-order LDS + scheduling fence
    hin[q][c][0] = ip[0]; hin[q][c][1] = ip[1]; hin[q][c][2] = ip[2];
    __builtin_amdgcn_wave_barrier();
    float pf[3], pd[3];
    matvec2(wf, wd, hin[q], c, pf, pd);
    __builtin_amdgcn_wave_barrier();
    vn_lrelu3(pf, pd);
    float* op = out + (size_t)p * 192 + c * 3;
    op[0] = pf[0]; op[1] = pf[1]; op[2] = pf[2];
  }
}

// ------- K4: Wc2 (VNT) -> xc; hc = h - xc in place; Wt (VNT,12) -> trans partials.
//         LDS ~50 KB -> 3 blocks/CU. -------
__global__ __launch_bounds__(256, 3) void c2t_kernel(
    const float* __restrict__ x2, float* __restrict__ h,
    const float* __restrict__ Wf, const float* __restrict__ Wd,
    const float* __restrict__ Wtf, const float* __restrict__ Wtd,
    float* __restrict__ trans_part) {
  __shared__ float wf[64][68], wd[64][68];
  __shared__ float wtf_[12][68], wtd_[12][68];
  __shared__ float hin[4][64][4], xc[4][64][4];
  __shared__ float tred[4][12][3];
  const int t = threadIdx.x;
  for (int e = t; e < 4096; e += 256) {
    wf[e >> 6][e & 63] = Wf[e]; wd[e >> 6][e & 63] = Wd[e];
  }
  for (int e = t; e < 768; e += 256) {            // FIX: was `if (t < 768)` with 256 threads
    wtf_[e >> 6][e & 63] = Wtf[e]; wtd_[e >> 6][e & 63] = Wtd[e];
  }
  __syncthreads();
  if (t < 64) {
    float s = 0.f;
    for (int i = 0; i < 64; ++i) s += wf[t][i];
    s = 1.0f / s;
    for (int i = 0; i < 64; ++i) wf[t][i] *= s;
  } else if (t < 76) {
    const int r = t - 64; float s = 0.f;
    for (int i = 0; i < 64; ++i) s += wtf_[r][i];
    s = 1.0f / s;
    for (int i = 0; i < 64; ++i) wtf_[r][i] *= s;
  }
  __syncthreads();
  const int q = t >> 6, c = t & 63;
  float ta0 = 0.f, ta1 = 0.f, ta2 = 0.f;
  for (int g = 0; g < 4; ++g) {
    const int p = (blockIdx.x << 4) + (g << 2) + q;
    const float* ip = x2 + (size_t)p * 192 + c * 3;
    hin[q][c][0] = ip[0]; hin[q][c][1] = ip[1]; hin[q][c][2] = ip[2];
    __builtin_amdgcn_wave_barrier();
    float qf[3], qd[3];
    matvec2(wf, wd, hin[q], c, qf, qd);
    __builtin_amdgcn_wave_barrier();
    vn_lrelu3(qf, qd);                       // qf = xc for channel c
    *(float4*)xc[q][c] = make_float4(qf[0], qf[1], qf[2], 0.f);
    __builtin_amdgcn_wave_barrier();
    float* hp = h + (size_t)p * 192 + c * 3; // hc = h - xc, in place
    hp[0] -= qf[0]; hp[1] -= qf[1]; hp[2] -= qf[2];
    if (c < 12) {
      float tf[3], td[3];
      matvec2(wtf_, wtd_, xc[q], c, tf, td);
      vn_lrelu3(tf, td);
      ta0 += tf[0]; ta1 += tf[1]; ta2 += tf[2];
    }
    __builtin_amdgcn_wave_barrier();
  }
  if (c < 12) { tred[q][c][0] = ta0; tred[q][c][1] = ta1; tred[q][c][2] = ta2; }
  __syncthreads();
  if (t < 36) {
    const int cc = t / 3, vv = t - cc * 3;
    trans_part[blockIdx.x * 36 + t] =
        tred[0][cc][vv] + tred[1][cc][vv] + tred[2][cc][vv] + tred[3][cc][vv];
  }
}

// ------- K5: W2 (VN) -> h2, summed over block's 16 points -> rot partials.
//         rred reuses hin. LDS 38.8 KB -> 4 blocks/CU. -------
__global__ __launch_bounds__(256, 4) void r2_kernel(
    const float* __restrict__ y1,
    const float* __restrict__ Wf, const float* __restrict__ Wd,
    float* __restrict__ rot_part) {
  __shared__ float wf[64][68], wd[64][68];
  __shared__ float hin[4][64][4];
  const int t = threadIdx.x;
  for (int e = t; e < 4096; e += 256) {
    wf[e >> 6][e & 63] = Wf[e]; wd[e >> 6][e & 63] = Wd[e];
  }
  __syncthreads();
  const int q = t >> 6, c = t & 63;
  float r0 = 0.f, r1 = 0.f, r2 = 0.f;
  for (int g = 0; g < 4; ++g) {
    const int p = (blockIdx.x << 4) + (g << 2) + q;
    const float* ip = y1 + (size_t)p * 192 + c * 3;
    hin[q][c][0] = ip[0]; hin[q][c][1] = ip[1]; hin[q][c][2] = ip[2];
    __builtin_amdgcn_wave_barrier();
    float pf[3], pd[3];
    matvec2(wf, wd, hin[q], c, pf, pd);
    __builtin_amdgcn_wave_barrier();
    vn_lrelu3(pf, pd);
    r0 += pf[0]; r1 += pf[1]; r2 += pf[2];
  }
  // reuse hin as the cross-wave reduction buffer
  *(float4*)hin[q][c] = make_float4(r0, r1, r2, 0.f);
  __syncthreads();
  if (t < 192) {
    const int cc = t / 3, vv = t - cc * 3;
    rot_part[blockIdx.x * 192 + t] =
        hin[0][cc][vv] + hin[1][cc][vv] + hin[2][cc][vv] + hin[3][cc][vv];
  }
}

// ------- K6: reduce partials, W3 @ mean(h2), concat [rot(116), trans(12)] -------
__global__ __launch_bounds__(384) void finalize_kernel(const float* __restrict__ rot_part,
                                                       const float* __restrict__ trans_part,
                                                       const float* __restrict__ W3,
                                                       float* __restrict__ out) {
  const int b = blockIdx.x;   // 0..3 (256 layer-blocks per batch)
  const int t = threadIdx.x;
  __shared__ float hsum[64][3];
  if (t < 192) {
    float s = 0.f;
    for (int blk = 0; blk < 256; ++blk)
      s += rot_part[(b * 256 + blk) * 192 + t];
    hsum[t / 3][t % 3] = s * (1.0f / NPTS);
  } else if (t < 228) {
    const int tt = t - 192;
    float s = 0.f;
    for (int blk = 0; blk < 256; ++blk)
      s += trans_part[(b * 256 + blk) * 36 + tt];
    out[b * 384 + 348 + tt] = s * (1.0f / NPTS);
  }
  __syncthreads();
  if (t < 348) {
    const int ch = t / 3, v = t - ch * 3;
    float s = 0.f;
    for (int i = 0; i < 64; ++i) s += W3[ch * 64 + i] * hsum[i][v];
    out[b * 384 + t] = s;
  }
}

extern "C" void kernel_launch(void* const* d_in, const int* in_sizes, int n_in,
                              void* d_out, int out_size, void* d_ws, size_t ws_size,
                              hipStream_t stream) {
  (void)in_sizes; (void)n_in; (void)out_size; (void)ws_size;
  const float* x     = (const float*)d_in[0];
  const float* Wposf = (const float*)d_in[1];
  const float* Wposd = (const float*)d_in[2];
  const float* Wc1f  = (const float*)d_in[3];
  const float* Wc1d  = (const float*)d_in[4];
  const float* Wc2f  = (const float*)d_in[5];
  const float* Wc2d  = (const float*)d_in[6];
  const float* Wtf   = (const float*)d_in[7];
  const float* Wtd   = (const float*)d_in[8];
  const float* W1f   = (const float*)d_in[9];
  const float* W1d   = (const float*)d_in[10];
  const float* W2f   = (const float*)d_in[11];
  const float* W2d   = (const float*)d_in[12];
  const float* W3    = (const float*)d_in[13];
  float* out = (float*)d_out;

  char* ws = (char*)d_ws;
  int*   knn        = (int*)ws;                          // 1,310,720 B
  float* P          = (float*)(ws + 1310720);            // 12,582,912 B: h, then hc (in place)
  float* Q          = (float*)(ws + 13893632);           // 12,582,912 B: x2, then y1
  float* trans_part = (float*)(ws + 26476544);           // 1024*36*4  = 147,456 B
  float* rot_part   = (float*)(ws + 26624000);           // 1024*192*4 = 786,432 B

  knn_kernel<<<BATCH * NPTS, 256, 0, stream>>>(x, knn);
  edge_kernel<<<BATCH * NPTS / 4, 256, 0, stream>>>(x, knn, Wposf, Wposd, P);
  layer_kernel<true><<<1024, 256, 0, stream>>>(P, Wc1f, Wc1d, Q);          // h -> x2
  c2t_kernel<<<1024, 256, 0, stream>>>(Q, P, Wc2f, Wc2d, Wtf, Wtd,
                                       trans_part);                         // x2 -> xc; P := h - xc
  layer_kernel<false><<<1024, 256, 0, stream>>>(P, W1f, W1d, Q);           // hc -> y1
  r2_kernel<<<1024, 256, 0, stream>>>(Q, W2f, W2d, rot_part);              // y1 -> rot partials
  finalize_kernel<<<BATCH, 384, 0, stream>>>(rot_part, trans_part, W3, out);
}

// Round 13
// 365.602 us; speedup vs baseline: 3.3731x; 1.8960x over previous
//
#include <hip/hip_runtime.h>

#define NPTS 4096
#define BATCH 4
#define KNN 20
#define ROT 116

__device__ __forceinline__ void vn_lrelu3(float p[3], const float d[3]) {
  float dot = p[0]*d[0] + p[1]*d[1] + p[2]*d[2];
  if (dot < 0.0f) {
    float dsq = d[0]*d[0] + d[1]*d[1] + d[2]*d[2];
    float r = dot / (dsq + 1e-6f);
    p[0] -= r*d[0]; p[1] -= r*d[1]; p[2] -= r*d[2];
  }
}

// LDS-weight dual matvec (used only for the small 12-row Wt): rows stride 68.
__device__ __forceinline__ void matvec2(const float wf[][68], const float wd[][68],
                                        const float src[][4], int c,
                                        float pf[3], float pd[3]) {
  float a0=0,a1=0,a2=0,b0=0,b1=0,b2=0;
#pragma unroll
  for (int i = 0; i < 64; i += 4) {
    const float4 f  = *(const float4*)&wf[c][i];
    const float4 d  = *(const float4*)&wd[c][i];
    const float4 h0 = *(const float4*)src[i+0];
    const float4 h1 = *(const float4*)src[i+1];
    const float4 h2 = *(const float4*)src[i+2];
    const float4 h3 = *(const float4*)src[i+3];
    a0 += f.x*h0.x + f.y*h1.x + f.z*h2.x + f.w*h3.x;
    a1 += f.x*h0.y + f.y*h1.y + f.z*h2.y + f.w*h3.y;
    a2 += f.x*h0.z + f.y*h1.z + f.z*h2.z + f.w*h3.z;
    b0 += d.x*h0.x + d.y*h1.x + d.z*h2.x + d.w*h3.x;
    b1 += d.x*h0.y + d.y*h1.y + d.z*h2.y + d.w*h3.y;
    b2 += d.x*h0.z + d.y*h1.z + d.z*h2.z + d.w*h3.z;
  }
  pf[0]=a0; pf[1]=a1; pf[2]=a2; pd[0]=b0; pd[1]=b1; pd[2]=b2;
}

// Register-weight dual matvec: WF/WD live in VGPRs (static indices only),
// src is the wave's broadcast LDS buffer (same-address reads = broadcast).
__device__ __forceinline__ void matvec_reg(const float4 WF[16], const float4 WD[16],
                                           const float src[][4],
                                           float pf[3], float pd[3]) {
  float a0=0,a1=0,a2=0,b0=0,b1=0,b2=0;
#pragma unroll
  for (int i = 0; i < 16; ++i) {
    const float4 f  = WF[i];
    const float4 d  = WD[i];
    const float4 h0 = *(const float4*)src[4*i+0];
    const float4 h1 = *(const float4*)src[4*i+1];
    const float4 h2 = *(const float4*)src[4*i+2];
    const float4 h3 = *(const float4*)src[4*i+3];
    a0 += f.x*h0.x + f.y*h1.x + f.z*h2.x + f.w*h3.x;
    a1 += f.x*h0.y + f.y*h1.y + f.z*h2.y + f.w*h3.y;
    a2 += f.x*h0.z + f.y*h1.z + f.z*h2.z + f.w*h3.z;
    b0 += d.x*h0.x + d.y*h1.x + d.z*h2.x + d.w*h3.x;
    b1 += d.x*h0.y + d.y*h1.y + d.z*h2.y + d.w*h3.y;
    b2 += d.x*h0.z + d.y*h1.z + d.z*h2.z + d.w*h3.z;
  }
  pf[0]=a0; pf[1]=a1; pf[2]=a2; pd[0]=b0; pd[1]=b1; pd[2]=b2;
}

// load lane's weight rows into registers; VNT row-norm is lane-local
template<bool VNT>
__device__ __forceinline__ void load_wreg(const float* __restrict__ Wf,
                                          const float* __restrict__ Wd,
                                          int c, float4 WF[16], float4 WD[16]) {
#pragma unroll
  for (int i = 0; i < 16; ++i) {
    WF[i] = *(const float4*)(Wf + c * 64 + i * 4);
    WD[i] = *(const float4*)(Wd + c * 64 + i * 4);
  }
  if (VNT) {
    float s = 0.f;
#pragma unroll
    for (int i = 0; i < 16; ++i) s += WF[i].x + WF[i].y + WF[i].z + WF[i].w;
    s = 1.0f / s;
#pragma unroll
    for (int i = 0; i < 16; ++i) {
      WF[i].x *= s; WF[i].y *= s; WF[i].z *= s; WF[i].w *= s;
    }
  }
}

// ---------------- K1: KNN via histogram select (unchanged) ----------------
__global__ __launch_bounds__(256) void knn_kernel(const float* __restrict__ x,
                                                  int* __restrict__ knn) {
  const int row = blockIdx.x;
  const int b = row >> 12, i = row & (NPTS - 1);
  const float* __restrict__ xb = x + b * 3 * NPTS;
  const float cx = xb[i], cy = xb[NPTS + i], cz = xb[2 * NPTS + i];
  const int t = threadIdx.x;
  const int j0 = t << 4;

  __shared__ unsigned int hist[2048];
  __shared__ unsigned int ld_[384];
  __shared__ int lj_[384];
  __shared__ unsigned int lcount;
  __shared__ int s_B;
  __shared__ int wtot[4];

  for (int k = t; k < 2048; k += 256) hist[k] = 0u;
  if (t == 0) lcount = 0u;
  __syncthreads();

  unsigned int db[16];
#pragma unroll
  for (int q = 0; q < 4; ++q) {
    const float4 px = *(const float4*)(xb + j0 + 4 * q);
    const float4 py = *(const float4*)(xb + NPTS + j0 + 4 * q);
    const float4 pz = *(const float4*)(xb + 2 * NPTS + j0 + 4 * q);
    float dx, dy, dz, dd;
    dx = px.x - cx; dy = py.x - cy; dz = pz.x - cz;
    dd = dx*dx + dy*dy + dz*dz; db[4*q+0] = __float_as_uint(dd);
    dx = px.y - cx; dy = py.y - cy; dz = pz.y - cz;
    dd = dx*dx + dy*dy + dz*dz; db[4*q+1] = __float_as_uint(dd);
    dx = px.z - cx; dy = py.z - cy; dz = pz.z - cz;
    dd = dx*dx + dy*dy + dz*dz; db[4*q+2] = __float_as_uint(dd);
    dx = px.w - cx; dy = py.w - cy; dz = pz.w - cz;
    dd = dx*dx + dy*dy + dz*dz; db[4*q+3] = __float_as_uint(dd);
  }
#pragma unroll
  for (int s = 0; s < 16; ++s) atomicAdd(&hist[db[s] >> 20], 1u);
  __syncthreads();

  int v = 0;
#pragma unroll
  for (int s = 0; s < 8; ++s) v += (int)hist[t * 8 + s];
  const int myps = v;
  const int lane = t & 63;
#pragma unroll
  for (int off = 1; off < 64; off <<= 1) {
    int n = __shfl_up(v, off);
    if (lane >= off) v += n;
  }
  if (lane == 63) wtot[t >> 6] = v;
  __syncthreads();
  int woff = 0;
#pragma unroll
  for (int w = 0; w < 4; ++w) if (w < (t >> 6)) woff += wtot[w];
  const int cum_in = v + woff;
  const int cum_ex = cum_in - myps;
  if (cum_ex < KNN && cum_in >= KNN) {
    int cum = cum_ex, B = t * 8;
    for (int s = 0; s < 8; ++s) {
      const int hh = (int)hist[t * 8 + s];
      if (cum + hh >= KNN) { B = t * 8 + s; break; }
      cum += hh;
    }
    s_B = B;
  }
  __syncthreads();
  const unsigned int Bb = (unsigned int)s_B;
#pragma unroll
  for (int s = 0; s < 16; ++s) {
    if ((db[s] >> 20) <= Bb) {
      unsigned int pos = atomicAdd(&lcount, 1u);
      if (pos < 384u) { ld_[pos] = db[s]; lj_[pos] = j0 + s; }
    }
  }
  __syncthreads();
  const int n = min((int)lcount, 384);
  for (int idx = t; idx < n; idx += 256) {
    const unsigned int kd = ld_[idx]; const int kj = lj_[idx];
    int rank = 0;
    for (int m = 0; m < n; ++m) {
      const unsigned int md = ld_[m];
      rank += (md < kd || (md == kd && lj_[m] < kj)) ? 1 : 0;
    }
    if (rank < KNN) knn[row * KNN + rank] = kj;
  }
}

// ------- K2: edge features + first VNT layer + mean over k (4 pts/block) -------
__global__ __launch_bounds__(256) void edge_kernel(const float* __restrict__ x,
                                                   const int* __restrict__ knn,
                                                   const float* __restrict__ Wf,
                                                   const float* __restrict__ Wd,
                                                   float* __restrict__ h) {
  const int g = threadIdx.x >> 6;
  const int lane = threadIdx.x & 63;
  const int p = (blockIdx.x << 2) + g;
  const int b = p >> 12, i = p & (NPTS - 1);
  const float* xb = x + b * 3 * NPTS;
  const float cx = xb[i], cy = xb[NPTS + i], cz = xb[2 * NPTS + i];
  __shared__ float e[4][KNN][3][3];
  if (lane < KNN) {
    int j = knn[p * KNN + lane];
    float nx = xb[j], ny = xb[NPTS + j], nz = xb[2 * NPTS + j];
    e[g][lane][0][0] = nx - cx; e[g][lane][0][1] = ny - cy; e[g][lane][0][2] = nz - cz;
    e[g][lane][1][0] = cx;      e[g][lane][1][1] = cy;      e[g][lane][1][2] = cz;
    e[g][lane][2][0] = ny * cz - nz * cy;
    e[g][lane][2][1] = nz * cx - nx * cz;
    e[g][lane][2][2] = nx * cy - ny * cx;
  }
  __syncthreads();
  const int c = lane;
  float f0 = Wf[c * 3 + 0], f1 = Wf[c * 3 + 1], f2 = Wf[c * 3 + 2];
  float s = 1.0f / (f0 + f1 + f2);
  f0 *= s; f1 *= s; f2 *= s;
  const float d0 = Wd[c * 3 + 0], d1 = Wd[c * 3 + 1], d2 = Wd[c * 3 + 2];
  float a0 = 0.f, a1 = 0.f, a2 = 0.f;
  for (int k = 0; k < KNN; ++k) {
    float pv[3], dv[3];
#pragma unroll
    for (int v = 0; v < 3; ++v) {
      pv[v] = f0 * e[g][k][0][v] + f1 * e[g][k][1][v] + f2 * e[g][k][2][v];
      dv[v] = d0 * e[g][k][0][v] + d1 * e[g][k][1][v] + d2 * e[g][k][2][v];
    }
    vn_lrelu3(pv, dv);
    a0 += pv[0]; a1 += pv[1]; a2 += pv[2];
  }
  const float inv = 1.0f / KNN;
  float* hp = h + p * 192 + c * 3;
  hp[0] = a0 * inv; hp[1] = a1 * inv; hp[2] = a2 * inv;
}

// ------- K3: one 64->64 VN(T) layer, weights in registers. -------
template<bool VNT>
__global__ __launch_bounds__(256) void layer_reg(
    const float* __restrict__ in,
    const float* __restrict__ Wf, const float* __restrict__ Wd,
    float* __restrict__ out) {
  const int t = threadIdx.x;
  const int q = t >> 6, c = t & 63;
  float4 WF[16], WD[16];
  load_wreg<VNT>(Wf, Wd, c, WF, WD);
  __shared__ float hin[4][64][4];
  const int pbase = (blockIdx.x * 4 + q) * 8;
  const float* ip = in + (size_t)pbase * 192 + c * 3;
  float h0 = ip[0], h1 = ip[1], h2 = ip[2];
  for (int g = 0; g < 8; ++g) {
    hin[q][c][0] = h0; hin[q][c][1] = h1; hin[q][c][2] = h2;
    __builtin_amdgcn_wave_barrier();
    if (g < 7) {                       // prefetch next point under the FMAs
      const float* np = in + (size_t)(pbase + g + 1) * 192 + c * 3;
      h0 = np[0]; h1 = np[1]; h2 = np[2];
    }
    float pf[3], pd[3];
    matvec_reg(WF, WD, hin[q], pf, pd);
    __builtin_amdgcn_wave_barrier();
    vn_lrelu3(pf, pd);
    float* op = out + (size_t)(pbase + g) * 192 + c * 3;
    op[0] = pf[0]; op[1] = pf[1]; op[2] = pf[2];
  }
}

// ------- K4: Wc2 (VNT, reg) -> xc; hc = h - xc (pure store); Wt (LDS) -> trans. -------
__global__ __launch_bounds__(256) void c2t_reg(
    const float* __restrict__ x2, float* __restrict__ h,
    const float* __restrict__ Wf, const float* __restrict__ Wd,
    const float* __restrict__ Wtf, const float* __restrict__ Wtd,
    float* __restrict__ trans_part) {
  const int t = threadIdx.x;
  const int q = t >> 6, c = t & 63;
  float4 WF[16], WD[16];
  load_wreg<true>(Wf, Wd, c, WF, WD);
  __shared__ float wtf_[12][68], wtd_[12][68];
  __shared__ float hin[4][64][4], xc[4][64][4];
  __shared__ float tred[4][12][3];
  for (int e = t; e < 768; e += 256) {
    wtf_[e >> 6][e & 63] = Wtf[e]; wtd_[e >> 6][e & 63] = Wtd[e];
  }
  __syncthreads();
  if (t < 12) {
    float s = 0.f;
    for (int i = 0; i < 64; ++i) s += wtf_[t][i];
    s = 1.0f / s;
    for (int i = 0; i < 64; ++i) wtf_[t][i] *= s;
  }
  __syncthreads();
  const int pbase = (blockIdx.x * 4 + q) * 8;
  const float* ip = x2 + (size_t)pbase * 192 + c * 3;
  const float* hp0 = h + (size_t)pbase * 192 + c * 3;
  float a0 = ip[0], a1 = ip[1], a2 = ip[2];
  float g0 = hp0[0], g1 = hp0[1], g2 = hp0[2];
  float ta0 = 0.f, ta1 = 0.f, ta2 = 0.f;
  for (int g = 0; g < 8; ++g) {
    const float cg0 = g0, cg1 = g1, cg2 = g2;   // current h BEFORE prefetch
    hin[q][c][0] = a0; hin[q][c][1] = a1; hin[q][c][2] = a2;
    __builtin_amdgcn_wave_barrier();
    if (g < 7) {
      const float* np = x2 + (size_t)(pbase + g + 1) * 192 + c * 3;
      const float* nh = h + (size_t)(pbase + g + 1) * 192 + c * 3;
      a0 = np[0]; a1 = np[1]; a2 = np[2];
      g0 = nh[0]; g1 = nh[1]; g2 = nh[2];
    }
    float qf[3], qd[3];
    matvec_reg(WF, WD, hin[q], qf, qd);
    __builtin_amdgcn_wave_barrier();
    vn_lrelu3(qf, qd);                          // qf = xc
    float* hcp = h + (size_t)(pbase + g) * 192 + c * 3;
    hcp[0] = cg0 - qf[0]; hcp[1] = cg1 - qf[1]; hcp[2] = cg2 - qf[2];
    *(float4*)xc[q][c] = make_float4(qf[0], qf[1], qf[2], 0.f);
    __builtin_amdgcn_wave_barrier();
    if (c < 12) {
      float tf[3], td[3];
      matvec2(wtf_, wtd_, xc[q], c, tf, td);
      vn_lrelu3(tf, td);
      ta0 += tf[0]; ta1 += tf[1]; ta2 += tf[2];
    }
    __builtin_amdgcn_wave_barrier();
  }
  if (c < 12) { tred[q][c][0] = ta0; tred[q][c][1] = ta1; tred[q][c][2] = ta2; }
  __syncthreads();
  if (t < 36) {
    const int cc = t / 3, vv = t - cc * 3;
    trans_part[blockIdx.x * 36 + t] =
        tred[0][cc][vv] + tred[1][cc][vv] + tred[2][cc][vv] + tred[3][cc][vv];
  }
}

// ------- K5: W2 (VN, reg) -> h2 summed over the wave's 8 points -> rot partials. -------
__global__ __launch_bounds__(256) void r2_reg(
    const float* __restrict__ y1,
    const float* __restrict__ Wf, const float* __restrict__ Wd,
    float* __restrict__ rot_part) {
  const int t = threadIdx.x;
  const int q = t >> 6, c = t & 63;
  float4 WF[16], WD[16];
  load_wreg<false>(Wf, Wd, c, WF, WD);
  __shared__ float hin[4][64][4];
  const int pbase = (blockIdx.x * 4 + q) * 8;
  const float* ip = y1 + (size_t)pbase * 192 + c * 3;
  float h0 = ip[0], h1 = ip[1], h2 = ip[2];
  float r0 = 0.f, r1 = 0.f, r2 = 0.f;
  for (int g = 0; g < 8; ++g) {
    hin[q][c][0] = h0; hin[q][c][1] = h1; hin[q][c][2] = h2;
    __builtin_amdgcn_wave_barrier();
    if (g < 7) {
      const float* np = y1 + (size_t)(pbase + g + 1) * 192 + c * 3;
      h0 = np[0]; h1 = np[1]; h2 = np[2];
    }
    float pf[3], pd[3];
    matvec_reg(WF, WD, hin[q], pf, pd);
    __builtin_amdgcn_wave_barrier();
    vn_lrelu3(pf, pd);
    r0 += pf[0]; r1 += pf[1]; r2 += pf[2];
  }
  *(float4*)hin[q][c] = make_float4(r0, r1, r2, 0.f);
  __syncthreads();
  if (t < 192) {
    const int cc = t / 3, vv = t - cc * 3;
    rot_part[blockIdx.x * 192 + t] =
        hin[0][cc][vv] + hin[1][cc][vv] + hin[2][cc][vv] + hin[3][cc][vv];
  }
}

// ------- K6: reduce partials, W3 @ mean(h2), concat [rot(116), trans(12)] -------
__global__ __launch_bounds__(384) void finalize_kernel(const float* __restrict__ rot_part,
                                                       const float* __restrict__ trans_part,
                                                       const float* __restrict__ W3,
                                                       float* __restrict__ out) {
  const int b = blockIdx.x;   // 0..3 (128 blocks per batch at grid 512)
  const int t = threadIdx.x;
  __shared__ float hsum[64][3];
  if (t < 192) {
    float s = 0.f;
    for (int blk = 0; blk < 128; ++blk)
      s += rot_part[(b * 128 + blk) * 192 + t];
    hsum[t / 3][t % 3] = s * (1.0f / NPTS);
  } else if (t < 228) {
    const int tt = t - 192;
    float s = 0.f;
    for (int blk = 0; blk < 128; ++blk)
      s += trans_part[(b * 128 + blk) * 36 + tt];
    out[b * 384 + 348 + tt] = s * (1.0f / NPTS);
  }
  __syncthreads();
  if (t < 348) {
    const int ch = t / 3, v = t - ch * 3;
    float s = 0.f;
    for (int i = 0; i < 64; ++i) s += W3[ch * 64 + i] * hsum[i][v];
    out[b * 384 + t] = s;
  }
}

extern "C" void kernel_launch(void* const* d_in, const int* in_sizes, int n_in,
                              void* d_out, int out_size, void* d_ws, size_t ws_size,
                              hipStream_t stream) {
  (void)in_sizes; (void)n_in; (void)out_size; (void)ws_size;
  const float* x     = (const float*)d_in[0];
  const float* Wposf = (const float*)d_in[1];
  const float* Wposd = (const float*)d_in[2];
  const float* Wc1f  = (const float*)d_in[3];
  const float* Wc1d  = (const float*)d_in[4];
  const float* Wc2f  = (const float*)d_in[5];
  const float* Wc2d  = (const float*)d_in[6];
  const float* Wtf   = (const float*)d_in[7];
  const float* Wtd   = (const float*)d_in[8];
  const float* W1f   = (const float*)d_in[9];
  const float* W1d   = (const float*)d_in[10];
  const float* W2f   = (const float*)d_in[11];
  const float* W2d   = (const float*)d_in[12];
  const float* W3    = (const float*)d_in[13];
  float* out = (float*)d_out;

  char* ws = (char*)d_ws;
  int*   knn        = (int*)ws;                          // 1,310,720 B
  float* P          = (float*)(ws + 1310720);            // 12,582,912 B: h, then hc (in place)
  float* Q          = (float*)(ws + 13893632);           // 12,582,912 B: x2, then y1
  float* trans_part = (float*)(ws + 26476544);           // 512*36*4  = 73,728 B
  float* rot_part   = (float*)(ws + 26550272);           // 512*192*4 = 393,216 B

  knn_kernel<<<BATCH * NPTS, 256, 0, stream>>>(x, knn);
  edge_kernel<<<BATCH * NPTS / 4, 256, 0, stream>>>(x, knn, Wposf, Wposd, P);
  layer_reg<true><<<512, 256, 0, stream>>>(P, Wc1f, Wc1d, Q);        // h -> x2
  c2t_reg<<<512, 256, 0, stream>>>(Q, P, Wc2f, Wc2d, Wtf, Wtd,
                                   trans_part);                       // x2 -> xc; P := h - xc
  layer_reg<false><<<512, 256, 0, stream>>>(P, W1f, W1d, Q);         // hc -> y1
  r2_reg<<<512, 256, 0, stream>>>(Q, W2f, W2d, rot_part);            // y1 -> rot partials
  finalize_kernel<<<BATCH, 384, 0, stream>>>(rot_part, trans_part, W3, out);
}